// Round 1
// baseline (621.846 us; speedup 1.0000x reference)
//
#include <hip/hip_runtime.h>

// Problem constants (from reference): B=8192 rows, ITEM_NUM=10000 cols.
#define ROWS 8192
#define COLS 10000
#define COLS4 (COLS / 4)   // 2500 float4 per row; 40000 B row stride is 16B-aligned
#define BLK 256

// One block per row. Computes dot(hidden[row], W) and dot(target[row], W) in a
// single pass (shared W load), applies the Q-learning epilogue, writes the
// per-row loss to partial[row]. No atomics -> no workspace zeroing needed.
__global__ __launch_bounds__(BLK) void qloss_rows_kernel(
    const float* __restrict__ hidden,
    const float* __restrict__ target,
    const float* __restrict__ rewards,
    const float* __restrict__ discount,   // 1-element
    const unsigned char* __restrict__ is_done,
    const float* __restrict__ W,          // [10000]
    const float* __restrict__ bias,       // 1-element
    float* __restrict__ partial)          // [ROWS]
{
    const int row = blockIdx.x;
    const float4* __restrict__ h4 = (const float4*)(hidden + (size_t)row * COLS);
    const float4* __restrict__ t4 = (const float4*)(target + (size_t)row * COLS);
    const float4* __restrict__ w4 = (const float4*)W;

    float ah = 0.f, at = 0.f;
    for (int j = threadIdx.x; j < COLS4; j += BLK) {
        float4 w = w4[j];
        float4 h = h4[j];
        float4 t = t4[j];
        ah += h.x * w.x + h.y * w.y + h.z * w.z + h.w * w.w;
        at += t.x * w.x + t.y * w.y + t.z * w.z + t.w * w.w;
    }

    // Wave (64-lane) reduction
    #pragma unroll
    for (int off = 32; off > 0; off >>= 1) {
        ah += __shfl_down(ah, off, 64);
        at += __shfl_down(at, off, 64);
    }

    __shared__ float sh[BLK / 64], st[BLK / 64];
    const int lane = threadIdx.x & 63;
    const int wid  = threadIdx.x >> 6;
    if (lane == 0) { sh[wid] = ah; st[wid] = at; }
    __syncthreads();

    if (threadIdx.x == 0) {
        float dh = sh[0] + sh[1] + sh[2] + sh[3];
        float dt = st[0] + st[1] + st[2] + st[3];
        float b  = bias[0];
        float q  = fmaxf(dh + b, 0.f);
        float nq = fmaxf(dt + b, 0.f);
        float loss = fabsf(rewards[row] + discount[0] * nq - q);
        partial[row] = is_done[row] ? 0.f : loss;
    }
}

// Single-block final reduction: sum 8192 partials, divide by B, write d_out[0].
// Must WRITE (not accumulate) since d_out is poisoned 0xAA before timed runs.
__global__ __launch_bounds__(BLK) void qloss_reduce_kernel(
    const float* __restrict__ partial,
    float* __restrict__ out)
{
    float s = 0.f;
    for (int i = threadIdx.x; i < ROWS; i += BLK) s += partial[i];

    #pragma unroll
    for (int off = 32; off > 0; off >>= 1) s += __shfl_down(s, off, 64);

    __shared__ float sm[BLK / 64];
    const int lane = threadIdx.x & 63;
    const int wid  = threadIdx.x >> 6;
    if (lane == 0) sm[wid] = s;
    __syncthreads();

    if (threadIdx.x == 0) {
        float total = sm[0] + sm[1] + sm[2] + sm[3];
        out[0] = total / (float)ROWS;
    }
}

extern "C" void kernel_launch(void* const* d_in, const int* in_sizes, int n_in,
                              void* d_out, int out_size, void* d_ws, size_t ws_size,
                              hipStream_t stream) {
    // setup_inputs() order:
    // 0: hidden_states [8192,10000] f32
    // 1: actions       [8192]       int32  (unused by reference)
    // 2: rewards       [8192]       f32
    // 3: discount      [1]          f32
    // 4: targetQs_s    [8192,10000] f32
    // 5: is_done       [8192]       bool (all false; read as bytes)
    // 6: W             [1,10000]    f32
    // 7: b             [1]          f32
    const float*         hidden   = (const float*)d_in[0];
    const float*         rewards  = (const float*)d_in[2];
    const float*         discount = (const float*)d_in[3];
    const float*         target   = (const float*)d_in[4];
    const unsigned char* is_done  = (const unsigned char*)d_in[5];
    const float*         W        = (const float*)d_in[6];
    const float*         b        = (const float*)d_in[7];
    float*               out      = (float*)d_out;
    float*               partial  = (float*)d_ws;   // needs ROWS*4 = 32 KB

    qloss_rows_kernel<<<ROWS, BLK, 0, stream>>>(
        hidden, target, rewards, discount, is_done, W, b, partial);
    qloss_reduce_kernel<<<1, BLK, 0, stream>>>(partial, out);
}

// Round 3
// 586.625 us; speedup vs baseline: 1.0600x; 1.0600x over previous
//
#include <hip/hip_runtime.h>

// Problem constants (from reference): B=8192 rows, ITEM_NUM=10000 cols.
#define ROWS 8192
#define COLS 10000
#define COLS4 (COLS / 4)     // 2500 float4 per row; 40000 B row stride (16B-aligned)
#define BLK 256
#define WAVES_PER_BLK (BLK / 64)

// Native clang vector type — accepted by __builtin_nontemporal_load
// (HIP's float4 is a class and is rejected).
typedef float vf4 __attribute__((ext_vector_type(4)));

__device__ __forceinline__ float dot4(vf4 a, vf4 b) {
    return a.x * b.x + a.y * b.y + a.z * b.z + a.w * b.w;
}

// One WAVE per row (4 rows per block). Computes dot(hidden[row],W) and
// dot(target[row],W) in one pass (shared W load), epilogue, writes per-row
// loss. No LDS, no __syncthreads. Streamed rows use nontemporal loads so the
// hot W vector stays L2-resident.
__global__ __launch_bounds__(BLK) void qloss_rows_kernel(
    const float* __restrict__ hidden,
    const float* __restrict__ target,
    const float* __restrict__ rewards,
    const float* __restrict__ discount,   // 1-element
    const unsigned char* __restrict__ is_done,
    const float* __restrict__ W,          // [10000]
    const float* __restrict__ bias,       // 1-element
    float* __restrict__ partial)          // [ROWS]
{
    const int lane = threadIdx.x & 63;
    const int wid  = threadIdx.x >> 6;
    const int row  = blockIdx.x * WAVES_PER_BLK + wid;

    const vf4* __restrict__ h4 = (const vf4*)(hidden + (size_t)row * COLS);
    const vf4* __restrict__ t4 = (const vf4*)(target + (size_t)row * COLS);
    const vf4* __restrict__ w4 = (const vf4*)W;

    // 2x unroll, two independent accumulator pairs -> 6 loads in flight/thread,
    // halved FMA dependency chain.
    float ah0 = 0.f, ah1 = 0.f, at0 = 0.f, at1 = 0.f;
    int j = lane;
    for (; j + 64 < COLS4; j += 128) {
        vf4 w0 = w4[j];
        vf4 w1 = w4[j + 64];
        vf4 h0 = __builtin_nontemporal_load(&h4[j]);
        vf4 h1 = __builtin_nontemporal_load(&h4[j + 64]);
        vf4 t0 = __builtin_nontemporal_load(&t4[j]);
        vf4 t1 = __builtin_nontemporal_load(&t4[j + 64]);
        ah0 += dot4(h0, w0);
        ah1 += dot4(h1, w1);
        at0 += dot4(t0, w0);
        at1 += dot4(t1, w1);
    }
    if (j < COLS4) {   // tail (COLS4 = 19*128 + 68)
        vf4 w0 = w4[j];
        vf4 h0 = __builtin_nontemporal_load(&h4[j]);
        vf4 t0 = __builtin_nontemporal_load(&t4[j]);
        ah0 += dot4(h0, w0);
        at0 += dot4(t0, w0);
    }

    float ah = ah0 + ah1;
    float at = at0 + at1;

    // Wave (64-lane) reduction
    #pragma unroll
    for (int off = 32; off > 0; off >>= 1) {
        ah += __shfl_down(ah, off, 64);
        at += __shfl_down(at, off, 64);
    }

    if (lane == 0) {
        float b  = bias[0];
        float q  = fmaxf(ah + b, 0.f);
        float nq = fmaxf(at + b, 0.f);
        float loss = fabsf(rewards[row] + discount[0] * nq - q);
        partial[row] = is_done[row] ? 0.f : loss;
    }
}

// Single-block final reduction: sum 8192 partials, divide by B, write d_out[0].
// Must WRITE (not accumulate) since d_out is poisoned 0xAA before timed runs.
__global__ __launch_bounds__(BLK) void qloss_reduce_kernel(
    const float* __restrict__ partial,
    float* __restrict__ out)
{
    float s = 0.f;
    for (int i = threadIdx.x; i < ROWS; i += BLK) s += partial[i];

    #pragma unroll
    for (int off = 32; off > 0; off >>= 1) s += __shfl_down(s, off, 64);

    __shared__ float sm[BLK / 64];
    const int lane = threadIdx.x & 63;
    const int wid  = threadIdx.x >> 6;
    if (lane == 0) sm[wid] = s;
    __syncthreads();

    if (threadIdx.x == 0) {
        float total = sm[0] + sm[1] + sm[2] + sm[3];
        out[0] = total / (float)ROWS;
    }
}

extern "C" void kernel_launch(void* const* d_in, const int* in_sizes, int n_in,
                              void* d_out, int out_size, void* d_ws, size_t ws_size,
                              hipStream_t stream) {
    // setup_inputs() order:
    // 0: hidden_states [8192,10000] f32
    // 1: actions       [8192]       int32  (unused by reference)
    // 2: rewards       [8192]       f32
    // 3: discount      [1]          f32
    // 4: targetQs_s    [8192,10000] f32
    // 5: is_done       [8192]       bool (all false; read as bytes)
    // 6: W             [1,10000]    f32
    // 7: b             [1]          f32
    const float*         hidden   = (const float*)d_in[0];
    const float*         rewards  = (const float*)d_in[2];
    const float*         discount = (const float*)d_in[3];
    const float*         target   = (const float*)d_in[4];
    const unsigned char* is_done  = (const unsigned char*)d_in[5];
    const float*         W        = (const float*)d_in[6];
    const float*         b        = (const float*)d_in[7];
    float*               out      = (float*)d_out;
    float*               partial  = (float*)d_ws;   // needs ROWS*4 = 32 KB

    qloss_rows_kernel<<<ROWS / WAVES_PER_BLK, BLK, 0, stream>>>(
        hidden, target, rewards, discount, is_done, W, b, partial);
    qloss_reduce_kernel<<<1, BLK, 0, stream>>>(partial, out);
}